// Round 2
// baseline (2183.732 us; speedup 1.0000x reference)
//
#include <hip/hip_runtime.h>
#include <math.h>

#define NPTS 9216          // 96*96
#define CDIM 256
#define WW 96
#define W2 192
#define MACT (192*192)
#define BM 128
#define BN 128
#define KB 16
#define NKC (CDIM / KB)    // 16
#define RB (NPTS / BM)     // 72 row blocks = col blocks

__device__ __forceinline__ void feed(float v, int i, float& v0, int& i0, float& v1, int& i1) {
    if (v > v0) { v1 = v0; i1 = i0; v0 = v; i0 = i; }
    else if (v > v1) { v1 = v; i1 = i; }
}

__device__ __forceinline__ float4 mul4(float4 a, float4 b) {
    a.x *= b.x; a.y *= b.y; a.z *= b.z; a.w *= b.w; return a;
}

// per-point inverse L2 norm over channels, map stored (C,N)
__global__ void norm_inv_k(const float* __restrict__ src, float* __restrict__ inv) {
    int p = blockIdx.x * blockDim.x + threadIdx.x;
    if (p >= NPTS) return;
    float s = 0.f;
    for (int c = 0; c < CDIM; ++c) { float v = src[(size_t)c * NPTS + p]; s += v * v; }
    inv[p] = 1.0f / sqrtf(s);
}

// sim = (A*invA)^T (B*invB); block (rb,cb) computes 128x128 tile, emits top2 partials.
__global__ __launch_bounds__(256) void sim_top2_k(const float* __restrict__ A, const float* __restrict__ B,
                                                  const float* __restrict__ invA, const float* __restrict__ invB,
                                                  float4* __restrict__ prow, float4* __restrict__ pcol) {
    alignas(16) __shared__ char smraw[34816];       // max(4*KB*BM*4 = 32768, 128*17*16 = 34816)
    float* sbuf = (float*)smraw;                    // A0 B0 A1 B1, each KB*BM floats
    float4 (*red)[17] = (float4 (*)[17])smraw;

    int rb = blockIdx.x, cb = blockIdx.y;
    int p0 = rb * BM, q0 = cb * BN;
    int tid = threadIdx.x;
    int tx = tid & 15, ty = tid >> 4;
    int sk = tid >> 4, sx = tid & 15;

    const float* Agp = A + (size_t)sk * NPTS + p0 + sx * 4;
    const float* Bgp = B + (size_t)sk * NPTS + q0 + sx * 4;
    float4 ivA0 = *(const float4*)&invA[p0 + sx * 4];
    float4 ivA1 = *(const float4*)&invA[p0 + 64 + sx * 4];
    float4 ivB0 = *(const float4*)&invB[q0 + sx * 4];
    float4 ivB1 = *(const float4*)&invB[q0 + 64 + sx * 4];

#define BUFA(d) (sbuf + (d) * 2 * KB * BM)
#define BUFB(d) (sbuf + (d) * 2 * KB * BM + KB * BM)

    // stage kc=0 into buffer 0
    {
        float4 ra0 = mul4(*(const float4*)(Agp), ivA0);
        float4 ra1 = mul4(*(const float4*)(Agp + 64), ivA1);
        float4 rb0 = mul4(*(const float4*)(Bgp), ivB0);
        float4 rb1 = mul4(*(const float4*)(Bgp + 64), ivB1);
        float* Ad = BUFA(0); float* Bd = BUFB(0);
        *(float4*)&Ad[sk * BM + sx * 4] = ra0;
        *(float4*)&Ad[sk * BM + 64 + sx * 4] = ra1;
        *(float4*)&Bd[sk * BM + sx * 4] = rb0;
        *(float4*)&Bd[sk * BM + 64 + sx * 4] = rb1;
    }
    __syncthreads();

    float acc[8][8];
    #pragma unroll
    for (int i = 0; i < 8; ++i)
        #pragma unroll
        for (int j = 0; j < 8; ++j) acc[i][j] = 0.f;

    for (int kc = 0; kc < NKC; ++kc) {
        int cur = kc & 1;
        float4 ra0, ra1, rb0, rb1;
        if (kc + 1 < NKC) {
            size_t off = (size_t)(kc + 1) * KB * NPTS;
            ra0 = mul4(*(const float4*)(Agp + off), ivA0);
            ra1 = mul4(*(const float4*)(Agp + off + 64), ivA1);
            rb0 = mul4(*(const float4*)(Bgp + off), ivB0);
            rb1 = mul4(*(const float4*)(Bgp + off + 64), ivB1);
        }
        const float* Ac = BUFA(cur);
        const float* Bc = BUFB(cur);
        #pragma unroll
        for (int kk = 0; kk < KB; ++kk) {
            float4 a0 = *(const float4*)&Ac[kk * BM + ty * 4];
            float4 a1 = *(const float4*)&Ac[kk * BM + 64 + ty * 4];
            float4 b0 = *(const float4*)&Bc[kk * BM + tx * 4];
            float4 b1 = *(const float4*)&Bc[kk * BM + 64 + tx * 4];
            float av[8] = {a0.x, a0.y, a0.z, a0.w, a1.x, a1.y, a1.z, a1.w};
            float bv[8] = {b0.x, b0.y, b0.z, b0.w, b1.x, b1.y, b1.z, b1.w};
            #pragma unroll
            for (int i = 0; i < 8; ++i)
                #pragma unroll
                for (int j = 0; j < 8; ++j) acc[i][j] += av[i] * bv[j];
        }
        if (kc + 1 < NKC) {
            float* Ad = BUFA(1 - cur); float* Bd = BUFB(1 - cur);
            *(float4*)&Ad[sk * BM + sx * 4] = ra0;
            *(float4*)&Ad[sk * BM + 64 + sx * 4] = ra1;
            *(float4*)&Bd[sk * BM + sx * 4] = rb0;
            *(float4*)&Bd[sk * BM + 64 + sx * 4] = rb1;
        }
        __syncthreads();
    }

    // ---- row top2 partials (per 128 rows of this tile, over its 128 cols) ----
    #pragma unroll
    for (int ri = 0; ri < 8; ++ri) {
        int grl = (ri < 4) ? ty * 4 + ri : 64 + ty * 4 + (ri - 4);
        float v0 = -3.0e38f, v1 = -3.0e38f; int i0 = 0, i1 = 0;
        #pragma unroll
        for (int cj = 0; cj < 8; ++cj) {
            int gc = q0 + ((cj < 4) ? tx * 4 + cj : 64 + tx * 4 + (cj - 4));
            feed(acc[ri][cj], gc, v0, i0, v1, i1);
        }
        red[grl][tx] = make_float4(v0, v1, __int_as_float(i0), __int_as_float(i1));
    }
    __syncthreads();
    if (tid < BM) {
        float v0 = -3.0e38f, v1 = -3.0e38f; int i0 = 0, i1 = 0;
        #pragma unroll
        for (int g = 0; g < 16; ++g) {
            float4 s = red[tid][g];
            feed(s.x, __float_as_int(s.z), v0, i0, v1, i1);
            feed(s.y, __float_as_int(s.w), v0, i0, v1, i1);
        }
        prow[(size_t)cb * NPTS + p0 + tid] = make_float4(v0, v1, __int_as_float(i0), __int_as_float(i1));
    }
    __syncthreads();

    // ---- col top2 partials ----
    #pragma unroll
    for (int cj = 0; cj < 8; ++cj) {
        int gcl = (cj < 4) ? tx * 4 + cj : 64 + tx * 4 + (cj - 4);
        float v0 = -3.0e38f, v1 = -3.0e38f; int i0 = 0, i1 = 0;
        #pragma unroll
        for (int ri = 0; ri < 8; ++ri) {
            int gr = p0 + ((ri < 4) ? ty * 4 + ri : 64 + ty * 4 + (ri - 4));
            feed(acc[ri][cj], gr, v0, i0, v1, i1);
        }
        red[gcl][ty] = make_float4(v0, v1, __int_as_float(i0), __int_as_float(i1));
    }
    __syncthreads();
    if (tid < BN) {
        float v0 = -3.0e38f, v1 = -3.0e38f; int i0 = 0, i1 = 0;
        #pragma unroll
        for (int g = 0; g < 16; ++g) {
            float4 s = red[tid][g];
            feed(s.x, __float_as_int(s.z), v0, i0, v1, i1);
            feed(s.y, __float_as_int(s.w), v0, i0, v1, i1);
        }
        pcol[(size_t)rb * NPTS + q0 + tid] = make_float4(v0, v1, __int_as_float(i0), __int_as_float(i1));
    }
}

__global__ void merge_rows_k(const float4* __restrict__ prow, int* __restrict__ nn12,
                             float* __restrict__ msim, float* __restrict__ r12) {
    int p = blockIdx.x * blockDim.x + threadIdx.x;
    if (p >= NPTS) return;
    float v0 = -3.0e38f, v1 = -3.0e38f; int i0 = 0, i1 = 0;
    for (int c = 0; c < RB; ++c) {
        float4 s = prow[(size_t)c * NPTS + p];
        feed(s.x, __float_as_int(s.z), v0, i0, v1, i1);
        feed(s.y, __float_as_int(s.w), v0, i0, v1, i1);
    }
    nn12[p] = i0; msim[p] = v0;
    r12[p] = (2.0f - 2.0f * v0) / ((2.0f - 2.0f * v1) + 1e-8f);
}

__global__ void merge_cols_k(const float4* __restrict__ pcol, int* __restrict__ nn21, float* __restrict__ r21) {
    int q = blockIdx.x * blockDim.x + threadIdx.x;
    if (q >= NPTS) return;
    float v0 = -3.0e38f, v1 = -3.0e38f; int i0 = 0, i1 = 0;
    for (int k = 0; k < RB; ++k) {
        float4 s = pcol[(size_t)k * NPTS + q];
        feed(s.x, __float_as_int(s.z), v0, i0, v1, i1);
        feed(s.y, __float_as_int(s.w), v0, i0, v1, i1);
    }
    nn21[q] = i0;
    r21[q] = (2.0f - 2.0f * v0) / ((2.0f - 2.0f * v1) + 1e-8f);
}

__global__ void valid_k(const int* __restrict__ nn12, const float* __restrict__ r12,
                        const int* __restrict__ nn21, const float* __restrict__ r21,
                        int* __restrict__ validv) {
    int p = blockIdx.x * blockDim.x + threadIdx.x;
    if (p >= NPTS) return;
    int nn = nn12[p];
    bool mnn = (nn21[nn] == p) && (r12[p] <= 0.95f) && (r21[nn] <= 0.95f);
    int xA = p % WW, yA = p / WW, xB = nn % WW, yB = nn / WW;
    bool disc = (xA == 0) | (xA == WW - 1) | (yA == 0) | (yA == WW - 1) |
                (xB == 0) | (xB == WW - 1) | (yB == 0) | (yB == WW - 1);
    validv[p] = (mnn && !disc) ? 1 : 0;
}

// one block (256 threads = 256 channels) per point
__global__ __launch_bounds__(256) void refine_k(const float* __restrict__ actA, const float* __restrict__ actB,
                                                const int* __restrict__ nn12, const float* __restrict__ msim,
                                                const int* __restrict__ validv, float* __restrict__ out) {
    int n = blockIdx.x;
    int c = threadIdx.x;
    int val = validv[n];
    int nn = nn12[n];
    int xA = n % WW, yA = n / WW;
    int xB = nn % WW, yB = nn / WW;
    int pAx = val ? 2 * xA : 2, pAy = val ? 2 * yA : 2;
    int pBx = val ? 2 * xB : 2, pBy = val ? 2 * yB : 2;
    const int nxv[4] = {0, 0, 1, 1};
    const int nyv[4] = {0, 1, 0, 1};
    float a[4], b[4];
    #pragma unroll
    for (int i = 0; i < 4; ++i) {
        a[i] = actA[(size_t)c * MACT + (pAy + nyv[i]) * W2 + pAx + nxv[i]];
        b[i] = actB[(size_t)c * MACT + (pBy + nyv[i]) * W2 + pBx + nxv[i]];
    }
    float vals[24];
    #pragma unroll
    for (int i = 0; i < 4; ++i) vals[i] = a[i] * a[i];
    #pragma unroll
    for (int j = 0; j < 4; ++j) vals[4 + j] = b[j] * b[j];
    #pragma unroll
    for (int i = 0; i < 4; ++i)
        #pragma unroll
        for (int j = 0; j < 4; ++j) vals[8 + i * 4 + j] = a[i] * b[j];
    #pragma unroll
    for (int v = 0; v < 24; ++v) {
        float x = vals[v];
        #pragma unroll
        for (int m = 1; m < 64; m <<= 1) x += __shfl_xor(x, m);
        vals[v] = x;
    }
    __shared__ float part[24][4];
    __shared__ float fin[24];
    int wave = c >> 6, lane = c & 63;
    if (lane == 0) {
        #pragma unroll
        for (int v = 0; v < 24; ++v) part[v][wave] = vals[v];
    }
    __syncthreads();
    if (c < 24) fin[c] = part[c][0] + part[c][1] + part[c][2] + part[c][3];
    __syncthreads();
    if (c == 0) {
        float rsA[4], rsB[4], sc[4][4];
        #pragma unroll
        for (int i = 0; i < 4; ++i) rsA[i] = 1.0f / sqrtf(fin[i]);
        #pragma unroll
        for (int j = 0; j < 4; ++j) rsB[j] = 1.0f / sqrtf(fin[4 + j]);
        #pragma unroll
        for (int i = 0; i < 4; ++i)
            #pragma unroll
            for (int j = 0; j < 4; ++j) sc[i][j] = fin[8 + i * 4 + j] * rsA[i] * rsB[j];

        float ratA[4], scoreA[4]; int mAB[4];
        #pragma unroll
        for (int i = 0; i < 4; ++i) {
            float v0 = -3.0e38f, v1 = -3.0e38f; int i0 = 0, i1 = 0;
            #pragma unroll
            for (int j = 0; j < 4; ++j) feed(sc[i][j], j, v0, i0, v1, i1);
            float d0 = 2.0f - 2.0f * v0, d1 = 2.0f - 2.0f * v1;
            ratA[i] = d0 / (d1 + 1e-8f);
            scoreA[i] = d0; mAB[i] = i0;
        }
        float ratB[4]; int mBA[4];
        #pragma unroll
        for (int j = 0; j < 4; ++j) {
            float v0 = -3.0e38f, v1 = -3.0e38f; int i0 = 0, i1 = 0;
            #pragma unroll
            for (int i = 0; i < 4; ++i) feed(sc[i][j], i, v0, i0, v1, i1);
            float d0 = 2.0f - 2.0f * v0, d1 = 2.0f - 2.0f * v1;
            ratB[j] = d0 / (d1 + 1e-8f);
            mBA[j] = i0;
        }
        bool rm[4];
        #pragma unroll
        for (int i = 0; i < 4; ++i) {
            bool cyc = (mBA[mAB[i]] == i);
            rm[i] = (fmaxf(ratA[i], ratB[i]) < 0.9f) && cyc;
        }
        float sm[4];
        #pragma unroll
        for (int i = 0; i < 4; ++i) sm[i] = rm[i] ? scoreA[i] : 5.0f;
        {
            float v0 = -3.0e38f, v1 = -3.0e38f; int i0 = 0, i1 = 0;
            #pragma unroll
            for (int i = 0; i < 4; ++i) feed(sm[i], i, v0, i0, v1, i1);
            rm[i0] = false; rm[i1] = false;
        }
        out[n * 5 + 0] = msim[n];
        #pragma unroll
        for (int i = 0; i < 4; ++i) out[n * 5 + 1 + i] = sm[i];
        size_t b2 = (size_t)NPTS * 5;
        #pragma unroll
        for (int i = 0; i < 4; ++i) out[b2 + (size_t)n * 4 + i] = (float)(pAx + nxv[i]);
        #pragma unroll
        for (int i = 0; i < 4; ++i) out[b2 + (size_t)NPTS * 4 + (size_t)n * 4 + i] = (float)(pAy + nyv[i]);
        size_t b3 = b2 + (size_t)NPTS * 8;
        #pragma unroll
        for (int i = 0; i < 4; ++i) out[b3 + (size_t)n * 4 + i] = (float)(pBx + nxv[mAB[i]]);
        #pragma unroll
        for (int i = 0; i < 4; ++i) out[b3 + (size_t)NPTS * 4 + (size_t)n * 4 + i] = (float)(pBy + nyv[mAB[i]]);
        size_t b4 = b3 + (size_t)NPTS * 8;
        #pragma unroll
        for (int i = 0; i < 4; ++i) out[b4 + (size_t)n * 4 + i] = (rm[i] && val) ? 1.0f : 0.0f;
    }
}

extern "C" void kernel_launch(void* const* d_in, const int* in_sizes, int n_in,
                              void* d_out, int out_size, void* d_ws, size_t ws_size,
                              hipStream_t stream) {
    const float* mapA = (const float*)d_in[0];
    const float* mapB = (const float*)d_in[1];
    const float* actA = (const float*)d_in[2];
    const float* actB = (const float*)d_in[3];
    float* out = (float*)d_out;

    float4* prow = (float4*)d_ws;                               // 72*9216 float4
    float4* pcol = prow + (size_t)RB * NPTS;                    // 72*9216 float4
    float* invA = (float*)(pcol + (size_t)RB * NPTS);
    float* invB = invA + NPTS;
    int* nn12 = (int*)(invB + NPTS);
    float* msim = (float*)(nn12 + NPTS);
    float* r12 = msim + NPTS;
    int* nn21 = (int*)(r12 + NPTS);
    float* r21 = (float*)(nn21 + NPTS);
    int* validv = (int*)(r21 + NPTS);

    norm_inv_k<<<NPTS / 256, 256, 0, stream>>>(mapA, invA);
    norm_inv_k<<<NPTS / 256, 256, 0, stream>>>(mapB, invB);
    dim3 g2(RB, RB);
    sim_top2_k<<<g2, 256, 0, stream>>>(mapA, mapB, invA, invB, prow, pcol);
    merge_rows_k<<<NPTS / 256, 256, 0, stream>>>(prow, nn12, msim, r12);
    merge_cols_k<<<NPTS / 256, 256, 0, stream>>>(pcol, nn21, r21);
    valid_k<<<NPTS / 256, 256, 0, stream>>>(nn12, r12, nn21, r21, validv);
    refine_k<<<NPTS, 256, 0, stream>>>(actA, actB, nn12, msim, validv, out);
}

// Round 3
// 1293.370 us; speedup vs baseline: 1.6884x; 1.6884x over previous
//
#include <hip/hip_runtime.h>
#include <math.h>

#define NPTS 9216          // 96*96
#define CDIM 256
#define WW 96
#define W2 192
#define MACT (192*192)
#define BM 128
#define RB (NPTS / BM)     // 72 row/col blocks

typedef __attribute__((ext_vector_type(8))) short short8;
typedef __attribute__((ext_vector_type(4))) float f32x4;

__device__ __forceinline__ void feed(float v, int i, float& v0, int& i0, float& v1, int& i1) {
    if (v > v0) { v1 = v0; i1 = i0; v0 = v; i0 = i; }
    else if (v > v1) { v1 = v; i1 = i; }
}

__device__ __forceinline__ unsigned short f2bf(float f) {
    unsigned u = __float_as_uint(f);
    unsigned r = (u + 0x7fffu + ((u >> 16) & 1u)) >> 16;   // RNE, no NaN inputs
    return (unsigned short)r;
}
__device__ __forceinline__ float bf2f(unsigned short h) {
    return __uint_as_float(((unsigned)h) << 16);
}

// per-point inverse L2 norm over channels, map stored (C,N)
__global__ void norm_inv_k(const float* __restrict__ src, float* __restrict__ inv) {
    int p = blockIdx.x * blockDim.x + threadIdx.x;
    if (p >= NPTS) return;
    float s = 0.f;
    for (int c = 0; c < CDIM; ++c) { float v = src[(size_t)c * NPTS + p]; s += v * v; }
    inv[p] = 1.0f / sqrtf(s);
}

// transpose (C,N) f32 -> (N,C) bf16 hi/lo of normalized values. Block: 64 p x 64 c.
__global__ __launch_bounds__(256) void prep_split_k(const float* __restrict__ src, const float* __restrict__ inv,
                                                    unsigned short* __restrict__ hiT, unsigned short* __restrict__ loT) {
    __shared__ float tile[64][65];
    int p0 = blockIdx.x * 64;
    int c0 = blockIdx.y * 64;
    int t = threadIdx.x;
    int cl = t >> 4, pl4 = (t & 15) * 4;
    #pragma unroll
    for (int i = 0; i < 4; ++i) {
        float4 v = *(const float4*)&src[(size_t)(c0 + i * 16 + cl) * NPTS + p0 + pl4];
        tile[i * 16 + cl][pl4] = v.x; tile[i * 16 + cl][pl4 + 1] = v.y;
        tile[i * 16 + cl][pl4 + 2] = v.z; tile[i * 16 + cl][pl4 + 3] = v.w;
    }
    __syncthreads();
    int pl = t >> 2, cs = t & 3;
    float iv = inv[p0 + pl];
    alignas(16) unsigned short hbuf[16], lbuf[16];
    #pragma unroll
    for (int j = 0; j < 16; ++j) {
        float v = tile[cs * 16 + j][pl] * iv;
        unsigned short h = f2bf(v);
        hbuf[j] = h;
        lbuf[j] = f2bf(v - bf2f(h));
    }
    size_t ob = (size_t)(p0 + pl) * 256 + c0 + cs * 16;
    *(uint4*)&hiT[ob] = *(const uint4*)&hbuf[0];
    *(uint4*)&hiT[ob + 8] = *(const uint4*)&hbuf[8];
    *(uint4*)&loT[ob] = *(const uint4*)&lbuf[0];
    *(uint4*)&loT[ob + 8] = *(const uint4*)&lbuf[8];
}

// sim tile GEMM: 128x128 per block, split-bf16 3-term MFMA, fused top2 partials.
__global__ __launch_bounds__(256) void sim_mfma_k(const unsigned short* __restrict__ AhT, const unsigned short* __restrict__ AlT,
                                                  const unsigned short* __restrict__ BhT, const unsigned short* __restrict__ BlT,
                                                  float4* __restrict__ prow, float4* __restrict__ pcol) {
    __shared__ __align__(16) unsigned short lds[16384];   // 32KB: Ah|Al|Bh|Bl each 128x32
    unsigned short* sAh = lds;
    unsigned short* sAl = lds + 4096;
    unsigned short* sBh = lds + 8192;
    unsigned short* sBl = lds + 12288;

    int rb = blockIdx.x, cb = blockIdx.y;
    int p0 = rb * 128, q0 = cb * 128;
    int t = threadIdx.x;
    int lane = t & 63, w = t >> 6;
    int wr = w >> 1, wc = w & 1;
    int l15 = lane & 15, kslot = lane >> 4;

    // staging: thread t covers rows (t>>2) and (t>>2)+64, 16B slot t&3, XOR-swizzled
    int srow = t >> 2, slot = t & 3;
    int ssw = (srow >> 1) & 3;
    int so0 = srow * 32 + ((slot ^ ssw) << 3);
    int so1 = so0 + 64 * 32;
    size_t gA0 = (size_t)(p0 + srow) * 256 + slot * 8;
    size_t gA1 = gA0 + (size_t)64 * 256;
    size_t gB0 = (size_t)(q0 + srow) * 256 + slot * 8;
    size_t gB1 = gB0 + (size_t)64 * 256;

    uint4 rg0, rg1, rg2, rg3, rg4, rg5, rg6, rg7;
#define LOADREGS(kc) { size_t o = (size_t)(kc) * 32; \
        rg0 = *(const uint4*)&AhT[gA0 + o]; rg1 = *(const uint4*)&AhT[gA1 + o]; \
        rg2 = *(const uint4*)&AlT[gA0 + o]; rg3 = *(const uint4*)&AlT[gA1 + o]; \
        rg4 = *(const uint4*)&BhT[gB0 + o]; rg5 = *(const uint4*)&BhT[gB1 + o]; \
        rg6 = *(const uint4*)&BlT[gB0 + o]; rg7 = *(const uint4*)&BlT[gB1 + o]; }
#define WRITELDS() { \
        *(uint4*)&sAh[so0] = rg0; *(uint4*)&sAh[so1] = rg1; \
        *(uint4*)&sAl[so0] = rg2; *(uint4*)&sAl[so1] = rg3; \
        *(uint4*)&sBh[so0] = rg4; *(uint4*)&sBh[so1] = rg5; \
        *(uint4*)&sBl[so0] = rg6; *(uint4*)&sBl[so1] = rg7; }

    LOADREGS(0); WRITELDS(); __syncthreads();

    f32x4 acc[4][4];
    #pragma unroll
    for (int i = 0; i < 4; ++i)
        #pragma unroll
        for (int j = 0; j < 4; ++j) acc[i][j] = (f32x4){0.f, 0.f, 0.f, 0.f};

    // fragment element offsets: row = (wr|wc)*64 + f*16 + l15; swizzle slot = kslot ^ ((l15>>1)&3)
    int fsw = (kslot ^ ((l15 >> 1) & 3)) << 3;
    int abase = (wr * 64 + l15) * 32 + fsw;
    int bbase = (wc * 64 + l15) * 32 + fsw;

    for (int kc = 0; kc < 8; ++kc) {
        if (kc < 7) LOADREGS(kc + 1);
        short8 ah[4], bh[4], xx[4];
        #pragma unroll
        for (int f = 0; f < 4; ++f) ah[f] = *(const short8*)&sAh[abase + f * 512];
        #pragma unroll
        for (int f = 0; f < 4; ++f) bh[f] = *(const short8*)&sBh[bbase + f * 512];
        #pragma unroll
        for (int i = 0; i < 4; ++i)
            #pragma unroll
            for (int j = 0; j < 4; ++j)
                acc[i][j] = __builtin_amdgcn_mfma_f32_16x16x32_bf16(ah[i], bh[j], acc[i][j], 0, 0, 0);
        #pragma unroll
        for (int f = 0; f < 4; ++f) xx[f] = *(const short8*)&sBl[bbase + f * 512];
        #pragma unroll
        for (int i = 0; i < 4; ++i)
            #pragma unroll
            for (int j = 0; j < 4; ++j)
                acc[i][j] = __builtin_amdgcn_mfma_f32_16x16x32_bf16(ah[i], xx[j], acc[i][j], 0, 0, 0);
        #pragma unroll
        for (int f = 0; f < 4; ++f) xx[f] = *(const short8*)&sAl[abase + f * 512];
        #pragma unroll
        for (int i = 0; i < 4; ++i)
            #pragma unroll
            for (int j = 0; j < 4; ++j)
                acc[i][j] = __builtin_amdgcn_mfma_f32_16x16x32_bf16(xx[i], bh[j], acc[i][j], 0, 0, 0);
        __syncthreads();
        if (kc < 7) { WRITELDS(); __syncthreads(); }
    }

    // ---- fused top-2 reductions (LDS reused after final barrier) ----
    float4* rowred = (float4*)lds;          // [128][2]
    float4* colred = (float4*)lds + 256;    // [128][2]

    #pragma unroll
    for (int f = 0; f < 4; ++f) {
        #pragma unroll
        for (int r = 0; r < 4; ++r) {
            float v0 = -3.0e38f, v1 = -3.0e38f; int i0 = 0, i1 = 0;
            #pragma unroll
            for (int fc = 0; fc < 4; ++fc)
                feed(acc[f][fc][r], q0 + wc * 64 + fc * 16 + l15, v0, i0, v1, i1);
            #pragma unroll
            for (int m = 1; m < 16; m <<= 1) {
                float pv0 = __shfl_xor(v0, m); int pi0 = __shfl_xor(i0, m);
                float pv1 = __shfl_xor(v1, m); int pi1 = __shfl_xor(i1, m);
                feed(pv0, pi0, v0, i0, v1, i1);
                feed(pv1, pi1, v0, i0, v1, i1);
            }
            if (l15 == 0) {
                int row = wr * 64 + f * 16 + kslot * 4 + r;
                rowred[row * 2 + wc] = make_float4(v0, v1, __int_as_float(i0), __int_as_float(i1));
            }
        }
    }
    #pragma unroll
    for (int fc = 0; fc < 4; ++fc) {
        float v0 = -3.0e38f, v1 = -3.0e38f; int i0 = 0, i1 = 0;
        #pragma unroll
        for (int f = 0; f < 4; ++f)
            #pragma unroll
            for (int r = 0; r < 4; ++r)
                feed(acc[f][fc][r], p0 + wr * 64 + f * 16 + kslot * 4 + r, v0, i0, v1, i1);
        #pragma unroll
        for (int m = 16; m < 64; m <<= 1) {
            float pv0 = __shfl_xor(v0, m); int pi0 = __shfl_xor(i0, m);
            float pv1 = __shfl_xor(v1, m); int pi1 = __shfl_xor(i1, m);
            feed(pv0, pi0, v0, i0, v1, i1);
            feed(pv1, pi1, v0, i0, v1, i1);
        }
        if (kslot == 0) {
            int col = wc * 64 + fc * 16 + l15;
            colred[col * 2 + wr] = make_float4(v0, v1, __int_as_float(i0), __int_as_float(i1));
        }
    }
    __syncthreads();
    if (t < 128) {
        float4 a = rowred[t * 2], b = rowred[t * 2 + 1];
        float v0 = a.x, v1 = a.y; int i0 = __float_as_int(a.z), i1 = __float_as_int(a.w);
        feed(b.x, __float_as_int(b.z), v0, i0, v1, i1);
        feed(b.y, __float_as_int(b.w), v0, i0, v1, i1);
        prow[(size_t)cb * NPTS + p0 + t] = make_float4(v0, v1, __int_as_float(i0), __int_as_float(i1));
        float4 c = colred[t * 2], d = colred[t * 2 + 1];
        v0 = c.x; v1 = c.y; i0 = __float_as_int(c.z); i1 = __float_as_int(c.w);
        feed(d.x, __float_as_int(d.z), v0, i0, v1, i1);
        feed(d.y, __float_as_int(d.w), v0, i0, v1, i1);
        pcol[(size_t)rb * NPTS + q0 + t] = make_float4(v0, v1, __int_as_float(i0), __int_as_float(i1));
    }
}

__global__ void merge_rows_k(const float4* __restrict__ prow, int* __restrict__ nn12,
                             float* __restrict__ msim, float* __restrict__ r12) {
    int p = blockIdx.x * blockDim.x + threadIdx.x;
    if (p >= NPTS) return;
    float v0 = -3.0e38f, v1 = -3.0e38f; int i0 = 0, i1 = 0;
    for (int c = 0; c < RB; ++c) {
        float4 s = prow[(size_t)c * NPTS + p];
        feed(s.x, __float_as_int(s.z), v0, i0, v1, i1);
        feed(s.y, __float_as_int(s.w), v0, i0, v1, i1);
    }
    nn12[p] = i0; msim[p] = v0;
    r12[p] = (2.0f - 2.0f * v0) / ((2.0f - 2.0f * v1) + 1e-8f);
}

__global__ void merge_cols_k(const float4* __restrict__ pcol, int* __restrict__ nn21, float* __restrict__ r21) {
    int q = blockIdx.x * blockDim.x + threadIdx.x;
    if (q >= NPTS) return;
    float v0 = -3.0e38f, v1 = -3.0e38f; int i0 = 0, i1 = 0;
    for (int k = 0; k < RB; ++k) {
        float4 s = pcol[(size_t)k * NPTS + q];
        feed(s.x, __float_as_int(s.z), v0, i0, v1, i1);
        feed(s.y, __float_as_int(s.w), v0, i0, v1, i1);
    }
    nn21[q] = i0;
    r21[q] = (2.0f - 2.0f * v0) / ((2.0f - 2.0f * v1) + 1e-8f);
}

__global__ void valid_k(const int* __restrict__ nn12, const float* __restrict__ r12,
                        const int* __restrict__ nn21, const float* __restrict__ r21,
                        int* __restrict__ validv) {
    int p = blockIdx.x * blockDim.x + threadIdx.x;
    if (p >= NPTS) return;
    int nn = nn12[p];
    bool mnn = (nn21[nn] == p) && (r12[p] <= 0.95f) && (r21[nn] <= 0.95f);
    int xA = p % WW, yA = p / WW, xB = nn % WW, yB = nn / WW;
    bool disc = (xA == 0) | (xA == WW - 1) | (yA == 0) | (yA == WW - 1) |
                (xB == 0) | (xB == WW - 1) | (yB == 0) | (yB == WW - 1);
    validv[p] = (mnn && !disc) ? 1 : 0;
}

// one block (256 threads = 256 channels) per point
__global__ __launch_bounds__(256) void refine_k(const float* __restrict__ actA, const float* __restrict__ actB,
                                                const int* __restrict__ nn12, const float* __restrict__ msim,
                                                const int* __restrict__ validv, float* __restrict__ out) {
    int n = blockIdx.x;
    int c = threadIdx.x;
    int val = validv[n];
    int nn = nn12[n];
    int xA = n % WW, yA = n / WW;
    int xB = nn % WW, yB = nn / WW;
    int pAx = val ? 2 * xA : 2, pAy = val ? 2 * yA : 2;
    int pBx = val ? 2 * xB : 2, pBy = val ? 2 * yB : 2;
    const int nxv[4] = {0, 0, 1, 1};
    const int nyv[4] = {0, 1, 0, 1};
    float a[4], b[4];
    #pragma unroll
    for (int i = 0; i < 4; ++i) {
        a[i] = actA[(size_t)c * MACT + (pAy + nyv[i]) * W2 + pAx + nxv[i]];
        b[i] = actB[(size_t)c * MACT + (pBy + nyv[i]) * W2 + pBx + nxv[i]];
    }
    float vals[24];
    #pragma unroll
    for (int i = 0; i < 4; ++i) vals[i] = a[i] * a[i];
    #pragma unroll
    for (int j = 0; j < 4; ++j) vals[4 + j] = b[j] * b[j];
    #pragma unroll
    for (int i = 0; i < 4; ++i)
        #pragma unroll
        for (int j = 0; j < 4; ++j) vals[8 + i * 4 + j] = a[i] * b[j];
    #pragma unroll
    for (int v = 0; v < 24; ++v) {
        float x = vals[v];
        #pragma unroll
        for (int m = 1; m < 64; m <<= 1) x += __shfl_xor(x, m);
        vals[v] = x;
    }
    __shared__ float part[24][4];
    __shared__ float fin[24];
    int wave = c >> 6, lane = c & 63;
    if (lane == 0) {
        #pragma unroll
        for (int v = 0; v < 24; ++v) part[v][wave] = vals[v];
    }
    __syncthreads();
    if (c < 24) fin[c] = part[c][0] + part[c][1] + part[c][2] + part[c][3];
    __syncthreads();
    if (c == 0) {
        float rsA[4], rsB[4], sc[4][4];
        #pragma unroll
        for (int i = 0; i < 4; ++i) rsA[i] = 1.0f / sqrtf(fin[i]);
        #pragma unroll
        for (int j = 0; j < 4; ++j) rsB[j] = 1.0f / sqrtf(fin[4 + j]);
        #pragma unroll
        for (int i = 0; i < 4; ++i)
            #pragma unroll
            for (int j = 0; j < 4; ++j) sc[i][j] = fin[8 + i * 4 + j] * rsA[i] * rsB[j];

        float ratA[4], scoreA[4]; int mAB[4];
        #pragma unroll
        for (int i = 0; i < 4; ++i) {
            float v0 = -3.0e38f, v1 = -3.0e38f; int i0 = 0, i1 = 0;
            #pragma unroll
            for (int j = 0; j < 4; ++j) feed(sc[i][j], j, v0, i0, v1, i1);
            float d0 = 2.0f - 2.0f * v0, d1 = 2.0f - 2.0f * v1;
            ratA[i] = d0 / (d1 + 1e-8f);
            scoreA[i] = d0; mAB[i] = i0;
        }
        float ratB[4]; int mBA[4];
        #pragma unroll
        for (int j = 0; j < 4; ++j) {
            float v0 = -3.0e38f, v1 = -3.0e38f; int i0 = 0, i1 = 0;
            #pragma unroll
            for (int i = 0; i < 4; ++i) feed(sc[i][j], i, v0, i0, v1, i1);
            float d0 = 2.0f - 2.0f * v0, d1 = 2.0f - 2.0f * v1;
            ratB[j] = d0 / (d1 + 1e-8f);
            mBA[j] = i0;
        }
        bool rm[4];
        #pragma unroll
        for (int i = 0; i < 4; ++i) {
            bool cyc = (mBA[mAB[i]] == i);
            rm[i] = (fmaxf(ratA[i], ratB[i]) < 0.9f) && cyc;
        }
        float sm[4];
        #pragma unroll
        for (int i = 0; i < 4; ++i) sm[i] = rm[i] ? scoreA[i] : 5.0f;
        {
            float v0 = -3.0e38f, v1 = -3.0e38f; int i0 = 0, i1 = 0;
            #pragma unroll
            for (int i = 0; i < 4; ++i) feed(sm[i], i, v0, i0, v1, i1);
            rm[i0] = false; rm[i1] = false;
        }
        out[n * 5 + 0] = msim[n];
        #pragma unroll
        for (int i = 0; i < 4; ++i) out[n * 5 + 1 + i] = sm[i];
        size_t b2 = (size_t)NPTS * 5;
        #pragma unroll
        for (int i = 0; i < 4; ++i) out[b2 + (size_t)n * 4 + i] = (float)(pAx + nxv[i]);
        #pragma unroll
        for (int i = 0; i < 4; ++i) out[b2 + (size_t)NPTS * 4 + (size_t)n * 4 + i] = (float)(pAy + nyv[i]);
        size_t b3 = b2 + (size_t)NPTS * 8;
        #pragma unroll
        for (int i = 0; i < 4; ++i) out[b3 + (size_t)n * 4 + i] = (float)(pBx + nxv[mAB[i]]);
        #pragma unroll
        for (int i = 0; i < 4; ++i) out[b3 + (size_t)NPTS * 4 + (size_t)n * 4 + i] = (float)(pBy + nyv[mAB[i]]);
        size_t b4 = b3 + (size_t)NPTS * 8;
        #pragma unroll
        for (int i = 0; i < 4; ++i) out[b4 + (size_t)n * 4 + i] = (rm[i] && val) ? 1.0f : 0.0f;
    }
}

extern "C" void kernel_launch(void* const* d_in, const int* in_sizes, int n_in,
                              void* d_out, int out_size, void* d_ws, size_t ws_size,
                              hipStream_t stream) {
    const float* mapA = (const float*)d_in[0];
    const float* mapB = (const float*)d_in[1];
    const float* actA = (const float*)d_in[2];
    const float* actB = (const float*)d_in[3];
    float* out = (float*)d_out;

    char* wsb = (char*)d_ws;
    size_t szT = (size_t)NPTS * 256 * sizeof(unsigned short);  // 4.72MB
    unsigned short* AhT = (unsigned short*)wsb;            wsb += szT;
    unsigned short* AlT = (unsigned short*)wsb;            wsb += szT;
    unsigned short* BhT = (unsigned short*)wsb;            wsb += szT;
    unsigned short* BlT = (unsigned short*)wsb;            wsb += szT;
    float4* prow = (float4*)wsb;                           wsb += (size_t)RB * NPTS * sizeof(float4);
    float4* pcol = (float4*)wsb;                           wsb += (size_t)RB * NPTS * sizeof(float4);
    float* invA = (float*)wsb;                             wsb += NPTS * sizeof(float);
    float* invB = (float*)wsb;                             wsb += NPTS * sizeof(float);
    int* nn12 = (int*)wsb;                                 wsb += NPTS * sizeof(int);
    float* msim = (float*)wsb;                             wsb += NPTS * sizeof(float);
    float* r12 = (float*)wsb;                              wsb += NPTS * sizeof(float);
    int* nn21 = (int*)wsb;                                 wsb += NPTS * sizeof(int);
    float* r21 = (float*)wsb;                              wsb += NPTS * sizeof(float);
    int* validv = (int*)wsb;

    norm_inv_k<<<NPTS / 256, 256, 0, stream>>>(mapA, invA);
    norm_inv_k<<<NPTS / 256, 256, 0, stream>>>(mapB, invB);
    dim3 gp(NPTS / 64, CDIM / 64);
    prep_split_k<<<gp, 256, 0, stream>>>(mapA, invA, AhT, AlT);
    prep_split_k<<<gp, 256, 0, stream>>>(mapB, invB, BhT, BlT);
    dim3 g2(RB, RB);
    sim_mfma_k<<<g2, 256, 0, stream>>>(AhT, AlT, BhT, BlT, prow, pcol);
    merge_rows_k<<<NPTS / 256, 256, 0, stream>>>(prow, nn12, msim, r12);
    merge_cols_k<<<NPTS / 256, 256, 0, stream>>>(pcol, nn21, r21);
    valid_k<<<NPTS / 256, 256, 0, stream>>>(nn12, r12, nn21, r21, validv);
    refine_k<<<NPTS, 256, 0, stream>>>(actA, actB, nn12, msim, validv, out);
}

// Round 4
// 1277.118 us; speedup vs baseline: 1.7099x; 1.0127x over previous
//
#include <hip/hip_runtime.h>
#include <math.h>

#define NPTS 9216          // 96*96
#define CDIM 256
#define WW 96
#define W2 192
#define MACT (192*192)
#define BM 128
#define RB (NPTS / BM)     // 72 row/col blocks

typedef __attribute__((ext_vector_type(8))) short short8;
typedef __attribute__((ext_vector_type(4))) float f32x4;

__device__ __forceinline__ void feed(float v, int i, float& v0, int& i0, float& v1, int& i1) {
    if (v > v0) { v1 = v0; i1 = i0; v0 = v; i0 = i; }
    else if (v > v1) { v1 = v; i1 = i; }
}

__device__ __forceinline__ unsigned short f2bf(float f) {
    unsigned u = __float_as_uint(f);
    unsigned r = (u + 0x7fffu + ((u >> 16) & 1u)) >> 16;   // RNE, no NaN inputs
    return (unsigned short)r;
}
__device__ __forceinline__ float bf2f(unsigned short h) {
    return __uint_as_float(((unsigned)h) << 16);
}

__device__ __forceinline__ void gload16(const unsigned short* g, unsigned short* l) {
    __builtin_amdgcn_global_load_lds((const __attribute__((address_space(1))) unsigned int*)g,
                                     (__attribute__((address_space(3))) unsigned int*)l, 16, 0, 0);
}

// per-point inverse L2 norm over channels, map stored (C,N)
__global__ void norm_inv_k(const float* __restrict__ src, float* __restrict__ inv) {
    int p = blockIdx.x * blockDim.x + threadIdx.x;
    if (p >= NPTS) return;
    float s = 0.f;
    for (int c = 0; c < CDIM; ++c) { float v = src[(size_t)c * NPTS + p]; s += v * v; }
    inv[p] = 1.0f / sqrtf(s);
}

// transpose (C,N) f32 -> (N,C) bf16 hi/lo of normalized values. Block: 64 p x 64 c.
__global__ __launch_bounds__(256) void prep_split_k(const float* __restrict__ src, const float* __restrict__ inv,
                                                    unsigned short* __restrict__ hiT, unsigned short* __restrict__ loT) {
    __shared__ float tile[64][65];
    int p0 = blockIdx.x * 64;
    int c0 = blockIdx.y * 64;
    int t = threadIdx.x;
    int cl = t >> 4, pl4 = (t & 15) * 4;
    #pragma unroll
    for (int i = 0; i < 4; ++i) {
        float4 v = *(const float4*)&src[(size_t)(c0 + i * 16 + cl) * NPTS + p0 + pl4];
        tile[i * 16 + cl][pl4] = v.x; tile[i * 16 + cl][pl4 + 1] = v.y;
        tile[i * 16 + cl][pl4 + 2] = v.z; tile[i * 16 + cl][pl4 + 3] = v.w;
    }
    __syncthreads();
    int pl = t >> 2, cs = t & 3;
    float iv = inv[p0 + pl];
    alignas(16) unsigned short hbuf[16], lbuf[16];
    #pragma unroll
    for (int j = 0; j < 16; ++j) {
        float v = tile[cs * 16 + j][pl] * iv;
        unsigned short h = f2bf(v);
        hbuf[j] = h;
        lbuf[j] = f2bf(v - bf2f(h));
    }
    size_t ob = (size_t)(p0 + pl) * 256 + c0 + cs * 16;
    *(uint4*)&hiT[ob] = *(const uint4*)&hbuf[0];
    *(uint4*)&hiT[ob + 8] = *(const uint4*)&hbuf[8];
    *(uint4*)&loT[ob] = *(const uint4*)&lbuf[0];
    *(uint4*)&loT[ob + 8] = *(const uint4*)&lbuf[8];
}

// sim tile GEMM: 128x128 per block, split-bf16 3-term MFMA, global_load_lds double-buffered.
__global__ __launch_bounds__(256) void sim_mfma_k(const unsigned short* __restrict__ AhT, const unsigned short* __restrict__ AlT,
                                                  const unsigned short* __restrict__ BhT, const unsigned short* __restrict__ BlT,
                                                  float4* __restrict__ prow, float4* __restrict__ pcol) {
    // 2 buffers x 4 streams x 128 rows x 32 elems (bf16) = 64 KB
    __shared__ __align__(16) unsigned short lds[32768];

    int rb = blockIdx.x, cb = blockIdx.y;
    int p0 = rb * 128, q0 = cb * 128;
    int t = threadIdx.x;
    int lane = t & 63, w = t >> 6;
    int wr = w >> 1, wc = w & 1;
    int l15 = lane & 15, kslot = lane >> 4;

    // ---- staging geometry (global source pre-swizzled, LDS linear) ----
    // wave w stages rows [w*16, w*16+16) and [64+w*16, ...) of each stream.
    int srow = w * 16 + (lane >> 2);           // 0..63 (chunk 0)
    int ssw = (srow >> 1) & 3;                 // same for srow+64
    int sgel = ((lane & 3) ^ ssw) * 8;         // swizzled element slot within 32-elem K-tile
    size_t gA0 = (size_t)(p0 + srow) * 256 + sgel;
    size_t gA1 = gA0 + (size_t)64 * 256;
    size_t gB0 = (size_t)(q0 + srow) * 256 + sgel;
    size_t gB1 = gB0 + (size_t)64 * 256;
    int lb0 = w * 512;                         // LDS elem base, chunk 0 (rows w*16.., 32 elems/row)
    int lb1 = 2048 + w * 512;                  // chunk 1 (rows 64+w*16..)

#define STAGE(b, kc) { size_t ko = (size_t)(kc) * 32; int bb = (b) * 16384; \
        gload16(AhT + gA0 + ko, &lds[bb          + lb0]); \
        gload16(AhT + gA1 + ko, &lds[bb          + lb1]); \
        gload16(AlT + gA0 + ko, &lds[bb +  4096  + lb0]); \
        gload16(AlT + gA1 + ko, &lds[bb +  4096  + lb1]); \
        gload16(BhT + gB0 + ko, &lds[bb +  8192  + lb0]); \
        gload16(BhT + gB1 + ko, &lds[bb +  8192  + lb1]); \
        gload16(BlT + gB0 + ko, &lds[bb + 12288  + lb0]); \
        gload16(BlT + gB1 + ko, &lds[bb + 12288  + lb1]); }

    STAGE(0, 0);

    f32x4 acc[4][4];
    #pragma unroll
    for (int i = 0; i < 4; ++i)
        #pragma unroll
        for (int j = 0; j < 4; ++j) acc[i][j] = (f32x4){0.f, 0.f, 0.f, 0.f};

    __syncthreads();   // drains vmcnt -> buf0 ready

    for (int kc = 0; kc < 8; ++kc) {
        if (kc < 7) STAGE((kc + 1) & 1, kc + 1);   // issue next-tile loads FIRST
        int bb = (kc & 1) * 16384;
        short8 ah[4], bh[4], xx[4];
        #pragma unroll
        for (int f = 0; f < 4; ++f) {
            int R = wr * 64 + f * 16 + l15;
            ah[f] = *(const short8*)&lds[bb + R * 32 + ((kslot ^ ((R >> 1) & 3)) << 3)];
        }
        #pragma unroll
        for (int f = 0; f < 4; ++f) {
            int R = wc * 64 + f * 16 + l15;
            bh[f] = *(const short8*)&lds[bb + 8192 + R * 32 + ((kslot ^ ((R >> 1) & 3)) << 3)];
        }
        #pragma unroll
        for (int i = 0; i < 4; ++i)
            #pragma unroll
            for (int j = 0; j < 4; ++j)
                acc[i][j] = __builtin_amdgcn_mfma_f32_16x16x32_bf16(ah[i], bh[j], acc[i][j], 0, 0, 0);
        #pragma unroll
        for (int f = 0; f < 4; ++f) {
            int R = wc * 64 + f * 16 + l15;
            xx[f] = *(const short8*)&lds[bb + 12288 + R * 32 + ((kslot ^ ((R >> 1) & 3)) << 3)];
        }
        #pragma unroll
        for (int i = 0; i < 4; ++i)
            #pragma unroll
            for (int j = 0; j < 4; ++j)
                acc[i][j] = __builtin_amdgcn_mfma_f32_16x16x32_bf16(ah[i], xx[j], acc[i][j], 0, 0, 0);
        #pragma unroll
        for (int f = 0; f < 4; ++f) {
            int R = wr * 64 + f * 16 + l15;
            xx[f] = *(const short8*)&lds[bb + 4096 + R * 32 + ((kslot ^ ((R >> 1) & 3)) << 3)];
        }
        #pragma unroll
        for (int i = 0; i < 4; ++i)
            #pragma unroll
            for (int j = 0; j < 4; ++j)
                acc[i][j] = __builtin_amdgcn_mfma_f32_16x16x32_bf16(xx[i], bh[j], acc[i][j], 0, 0, 0);
        __syncthreads();   // single barrier: drains this iter's gload_lds + ds_reads
    }

    // ---- fused top-2 reductions (LDS reused after final barrier) ----
    float4* rowred = (float4*)lds;          // [128][2]
    float4* colred = (float4*)lds + 256;    // [128][2]

    #pragma unroll
    for (int f = 0; f < 4; ++f) {
        #pragma unroll
        for (int r = 0; r < 4; ++r) {
            float v0 = -3.0e38f, v1 = -3.0e38f; int i0 = 0, i1 = 0;
            #pragma unroll
            for (int fc = 0; fc < 4; ++fc)
                feed(acc[f][fc][r], q0 + wc * 64 + fc * 16 + l15, v0, i0, v1, i1);
            #pragma unroll
            for (int m = 1; m < 16; m <<= 1) {
                float pv0 = __shfl_xor(v0, m); int pi0 = __shfl_xor(i0, m);
                float pv1 = __shfl_xor(v1, m); int pi1 = __shfl_xor(i1, m);
                feed(pv0, pi0, v0, i0, v1, i1);
                feed(pv1, pi1, v0, i0, v1, i1);
            }
            if (l15 == 0) {
                int row = wr * 64 + f * 16 + kslot * 4 + r;
                rowred[row * 2 + wc] = make_float4(v0, v1, __int_as_float(i0), __int_as_float(i1));
            }
        }
    }
    #pragma unroll
    for (int fc = 0; fc < 4; ++fc) {
        float v0 = -3.0e38f, v1 = -3.0e38f; int i0 = 0, i1 = 0;
        #pragma unroll
        for (int f = 0; f < 4; ++f)
            #pragma unroll
            for (int r = 0; r < 4; ++r)
                feed(acc[f][fc][r], p0 + wr * 64 + f * 16 + kslot * 4 + r, v0, i0, v1, i1);
        #pragma unroll
        for (int m = 16; m < 64; m <<= 1) {
            float pv0 = __shfl_xor(v0, m); int pi0 = __shfl_xor(i0, m);
            float pv1 = __shfl_xor(v1, m); int pi1 = __shfl_xor(i1, m);
            feed(pv0, pi0, v0, i0, v1, i1);
            feed(pv1, pi1, v0, i0, v1, i1);
        }
        if (kslot == 0) {
            int col = wc * 64 + fc * 16 + l15;
            colred[col * 2 + wr] = make_float4(v0, v1, __int_as_float(i0), __int_as_float(i1));
        }
    }
    __syncthreads();
    if (t < 128) {
        float4 a = rowred[t * 2], b = rowred[t * 2 + 1];
        float v0 = a.x, v1 = a.y; int i0 = __float_as_int(a.z), i1 = __float_as_int(a.w);
        feed(b.x, __float_as_int(b.z), v0, i0, v1, i1);
        feed(b.y, __float_as_int(b.w), v0, i0, v1, i1);
        prow[(size_t)cb * NPTS + p0 + t] = make_float4(v0, v1, __int_as_float(i0), __int_as_float(i1));
        float4 c = colred[t * 2], d = colred[t * 2 + 1];
        v0 = c.x; v1 = c.y; i0 = __float_as_int(c.z); i1 = __float_as_int(c.w);
        feed(d.x, __float_as_int(d.z), v0, i0, v1, i1);
        feed(d.y, __float_as_int(d.w), v0, i0, v1, i1);
        pcol[(size_t)rb * NPTS + q0 + t] = make_float4(v0, v1, __int_as_float(i0), __int_as_float(i1));
    }
}

__global__ void merge_rows_k(const float4* __restrict__ prow, int* __restrict__ nn12,
                             float* __restrict__ msim, float* __restrict__ r12) {
    int p = blockIdx.x * blockDim.x + threadIdx.x;
    if (p >= NPTS) return;
    float v0 = -3.0e38f, v1 = -3.0e38f; int i0 = 0, i1 = 0;
    for (int c = 0; c < RB; ++c) {
        float4 s = prow[(size_t)c * NPTS + p];
        feed(s.x, __float_as_int(s.z), v0, i0, v1, i1);
        feed(s.y, __float_as_int(s.w), v0, i0, v1, i1);
    }
    nn12[p] = i0; msim[p] = v0;
    r12[p] = (2.0f - 2.0f * v0) / ((2.0f - 2.0f * v1) + 1e-8f);
}

__global__ void merge_cols_k(const float4* __restrict__ pcol, int* __restrict__ nn21, float* __restrict__ r21) {
    int q = blockIdx.x * blockDim.x + threadIdx.x;
    if (q >= NPTS) return;
    float v0 = -3.0e38f, v1 = -3.0e38f; int i0 = 0, i1 = 0;
    for (int k = 0; k < RB; ++k) {
        float4 s = pcol[(size_t)k * NPTS + q];
        feed(s.x, __float_as_int(s.z), v0, i0, v1, i1);
        feed(s.y, __float_as_int(s.w), v0, i0, v1, i1);
    }
    nn21[q] = i0;
    r21[q] = (2.0f - 2.0f * v0) / ((2.0f - 2.0f * v1) + 1e-8f);
}

__global__ void valid_k(const int* __restrict__ nn12, const float* __restrict__ r12,
                        const int* __restrict__ nn21, const float* __restrict__ r21,
                        int* __restrict__ validv) {
    int p = blockIdx.x * blockDim.x + threadIdx.x;
    if (p >= NPTS) return;
    int nn = nn12[p];
    bool mnn = (nn21[nn] == p) && (r12[p] <= 0.95f) && (r21[nn] <= 0.95f);
    int xA = p % WW, yA = p / WW, xB = nn % WW, yB = nn / WW;
    bool disc = (xA == 0) | (xA == WW - 1) | (yA == 0) | (yA == WW - 1) |
                (xB == 0) | (xB == WW - 1) | (yB == 0) | (yB == WW - 1);
    validv[p] = (mnn && !disc) ? 1 : 0;
}

// one block (256 threads = 256 channels) per point
__global__ __launch_bounds__(256) void refine_k(const float* __restrict__ actA, const float* __restrict__ actB,
                                                const int* __restrict__ nn12, const float* __restrict__ msim,
                                                const int* __restrict__ validv, float* __restrict__ out) {
    int n = blockIdx.x;
    int c = threadIdx.x;
    int val = validv[n];
    int nn = nn12[n];
    int xA = n % WW, yA = n / WW;
    int xB = nn % WW, yB = nn / WW;
    int pAx = val ? 2 * xA : 2, pAy = val ? 2 * yA : 2;
    int pBx = val ? 2 * xB : 2, pBy = val ? 2 * yB : 2;
    const int nxv[4] = {0, 0, 1, 1};
    const int nyv[4] = {0, 1, 0, 1};
    float a[4], b[4];
    #pragma unroll
    for (int i = 0; i < 4; ++i) {
        a[i] = actA[(size_t)c * MACT + (pAy + nyv[i]) * W2 + pAx + nxv[i]];
        b[i] = actB[(size_t)c * MACT + (pBy + nyv[i]) * W2 + pBx + nxv[i]];
    }
    float vals[24];
    #pragma unroll
    for (int i = 0; i < 4; ++i) vals[i] = a[i] * a[i];
    #pragma unroll
    for (int j = 0; j < 4; ++j) vals[4 + j] = b[j] * b[j];
    #pragma unroll
    for (int i = 0; i < 4; ++i)
        #pragma unroll
        for (int j = 0; j < 4; ++j) vals[8 + i * 4 + j] = a[i] * b[j];
    #pragma unroll
    for (int v = 0; v < 24; ++v) {
        float x = vals[v];
        #pragma unroll
        for (int m = 1; m < 64; m <<= 1) x += __shfl_xor(x, m);
        vals[v] = x;
    }
    __shared__ float part[24][4];
    __shared__ float fin[24];
    int wave = c >> 6, lane = c & 63;
    if (lane == 0) {
        #pragma unroll
        for (int v = 0; v < 24; ++v) part[v][wave] = vals[v];
    }
    __syncthreads();
    if (c < 24) fin[c] = part[c][0] + part[c][1] + part[c][2] + part[c][3];
    __syncthreads();
    if (c == 0) {
        float rsA[4], rsB[4], sc[4][4];
        #pragma unroll
        for (int i = 0; i < 4; ++i) rsA[i] = 1.0f / sqrtf(fin[i]);
        #pragma unroll
        for (int j = 0; j < 4; ++j) rsB[j] = 1.0f / sqrtf(fin[4 + j]);
        #pragma unroll
        for (int i = 0; i < 4; ++i)
            #pragma unroll
            for (int j = 0; j < 4; ++j) sc[i][j] = fin[8 + i * 4 + j] * rsA[i] * rsB[j];

        float ratA[4], scoreA[4]; int mAB[4];
        #pragma unroll
        for (int i = 0; i < 4; ++i) {
            float v0 = -3.0e38f, v1 = -3.0e38f; int i0 = 0, i1 = 0;
            #pragma unroll
            for (int j = 0; j < 4; ++j) feed(sc[i][j], j, v0, i0, v1, i1);
            float d0 = 2.0f - 2.0f * v0, d1 = 2.0f - 2.0f * v1;
            ratA[i] = d0 / (d1 + 1e-8f);
            scoreA[i] = d0; mAB[i] = i0;
        }
        float ratB[4]; int mBA[4];
        #pragma unroll
        for (int j = 0; j < 4; ++j) {
            float v0 = -3.0e38f, v1 = -3.0e38f; int i0 = 0, i1 = 0;
            #pragma unroll
            for (int i = 0; i < 4; ++i) feed(sc[i][j], i, v0, i0, v1, i1);
            float d0 = 2.0f - 2.0f * v0, d1 = 2.0f - 2.0f * v1;
            ratB[j] = d0 / (d1 + 1e-8f);
            mBA[j] = i0;
        }
        bool rm[4];
        #pragma unroll
        for (int i = 0; i < 4; ++i) {
            bool cyc = (mBA[mAB[i]] == i);
            rm[i] = (fmaxf(ratA[i], ratB[i]) < 0.9f) && cyc;
        }
        float sm[4];
        #pragma unroll
        for (int i = 0; i < 4; ++i) sm[i] = rm[i] ? scoreA[i] : 5.0f;
        {
            float v0 = -3.0e38f, v1 = -3.0e38f; int i0 = 0, i1 = 0;
            #pragma unroll
            for (int i = 0; i < 4; ++i) feed(sm[i], i, v0, i0, v1, i1);
            rm[i0] = false; rm[i1] = false;
        }
        out[n * 5 + 0] = msim[n];
        #pragma unroll
        for (int i = 0; i < 4; ++i) out[n * 5 + 1 + i] = sm[i];
        size_t b2 = (size_t)NPTS * 5;
        #pragma unroll
        for (int i = 0; i < 4; ++i) out[b2 + (size_t)n * 4 + i] = (float)(pAx + nxv[i]);
        #pragma unroll
        for (int i = 0; i < 4; ++i) out[b2 + (size_t)NPTS * 4 + (size_t)n * 4 + i] = (float)(pAy + nyv[i]);
        size_t b3 = b2 + (size_t)NPTS * 8;
        #pragma unroll
        for (int i = 0; i < 4; ++i) out[b3 + (size_t)n * 4 + i] = (float)(pBx + nxv[mAB[i]]);
        #pragma unroll
        for (int i = 0; i < 4; ++i) out[b3 + (size_t)NPTS * 4 + (size_t)n * 4 + i] = (float)(pBy + nyv[mAB[i]]);
        size_t b4 = b3 + (size_t)NPTS * 8;
        #pragma unroll
        for (int i = 0; i < 4; ++i) out[b4 + (size_t)n * 4 + i] = (rm[i] && val) ? 1.0f : 0.0f;
    }
}

extern "C" void kernel_launch(void* const* d_in, const int* in_sizes, int n_in,
                              void* d_out, int out_size, void* d_ws, size_t ws_size,
                              hipStream_t stream) {
    const float* mapA = (const float*)d_in[0];
    const float* mapB = (const float*)d_in[1];
    const float* actA = (const float*)d_in[2];
    const float* actB = (const float*)d_in[3];
    float* out = (float*)d_out;

    char* wsb = (char*)d_ws;
    size_t szT = (size_t)NPTS * 256 * sizeof(unsigned short);  // 4.72MB
    unsigned short* AhT = (unsigned short*)wsb;            wsb += szT;
    unsigned short* AlT = (unsigned short*)wsb;            wsb += szT;
    unsigned short* BhT = (unsigned short*)wsb;            wsb += szT;
    unsigned short* BlT = (unsigned short*)wsb;            wsb += szT;
    float4* prow = (float4*)wsb;                           wsb += (size_t)RB * NPTS * sizeof(float4);
    float4* pcol = (float4*)wsb;                           wsb += (size_t)RB * NPTS * sizeof(float4);
    float* invA = (float*)wsb;                             wsb += NPTS * sizeof(float);
    float* invB = (float*)wsb;                             wsb += NPTS * sizeof(float);
    int* nn12 = (int*)wsb;                                 wsb += NPTS * sizeof(int);
    float* msim = (float*)wsb;                             wsb += NPTS * sizeof(float);
    float* r12 = (float*)wsb;                              wsb += NPTS * sizeof(float);
    int* nn21 = (int*)wsb;                                 wsb += NPTS * sizeof(int);
    float* r21 = (float*)wsb;                              wsb += NPTS * sizeof(float);
    int* validv = (int*)wsb;

    norm_inv_k<<<NPTS / 256, 256, 0, stream>>>(mapA, invA);
    norm_inv_k<<<NPTS / 256, 256, 0, stream>>>(mapB, invB);
    dim3 gp(NPTS / 64, CDIM / 64);
    prep_split_k<<<gp, 256, 0, stream>>>(mapA, invA, AhT, AlT);
    prep_split_k<<<gp, 256, 0, stream>>>(mapB, invB, BhT, BlT);
    dim3 g2(RB, RB);
    sim_mfma_k<<<g2, 256, 0, stream>>>(AhT, AlT, BhT, BlT, prow, pcol);
    merge_rows_k<<<NPTS / 256, 256, 0, stream>>>(prow, nn12, msim, r12);
    merge_cols_k<<<NPTS / 256, 256, 0, stream>>>(pcol, nn21, r21);
    valid_k<<<NPTS / 256, 256, 0, stream>>>(nn12, r12, nn21, r21, validv);
    refine_k<<<NPTS, 256, 0, stream>>>(actA, actB, nn12, msim, validv, out);
}

// Round 5
// 1275.408 us; speedup vs baseline: 1.7122x; 1.0013x over previous
//
#include <hip/hip_runtime.h>
#include <math.h>

#define NPTS 9216          // 96*96
#define CDIM 256
#define WW 96
#define W2 192
#define MACT (192*192)
#define BM 128
#define RB (NPTS / BM)     // 72 row/col blocks
#define NXCD 8
#define STRIPE (RB / NXCD) // 9 row-blocks per XCD stripe

typedef __attribute__((ext_vector_type(8))) short short8;
typedef __attribute__((ext_vector_type(4))) float f32x4;

__device__ __forceinline__ void feed(float v, int i, float& v0, int& i0, float& v1, int& i1) {
    if (v > v0) { v1 = v0; i1 = i0; v0 = v; i0 = i; }
    else if (v > v1) { v1 = v; i1 = i; }
}

__device__ __forceinline__ unsigned short f2bf(float f) {
    unsigned u = __float_as_uint(f);
    unsigned r = (u + 0x7fffu + ((u >> 16) & 1u)) >> 16;   // RNE, no NaN inputs
    return (unsigned short)r;
}
__device__ __forceinline__ float bf2f(unsigned short h) {
    return __uint_as_float(((unsigned)h) << 16);
}

__device__ __forceinline__ void gload16(const unsigned short* g, unsigned short* l) {
    __builtin_amdgcn_global_load_lds((const __attribute__((address_space(1))) unsigned int*)g,
                                     (__attribute__((address_space(3))) unsigned int*)l, 16, 0, 0);
}

// per-point inverse L2 norm over channels, map stored (C,N)
__global__ void norm_inv_k(const float* __restrict__ src, float* __restrict__ inv) {
    int p = blockIdx.x * blockDim.x + threadIdx.x;
    if (p >= NPTS) return;
    float s = 0.f;
    for (int c = 0; c < CDIM; ++c) { float v = src[(size_t)c * NPTS + p]; s += v * v; }
    inv[p] = 1.0f / sqrtf(s);
}

// transpose (C,N) f32 -> (N,C) bf16 hi/lo of normalized values. Block: 64 p x 64 c.
__global__ __launch_bounds__(256) void prep_split_k(const float* __restrict__ src, const float* __restrict__ inv,
                                                    unsigned short* __restrict__ hiT, unsigned short* __restrict__ loT) {
    __shared__ float tile[64][65];
    int p0 = blockIdx.x * 64;
    int c0 = blockIdx.y * 64;
    int t = threadIdx.x;
    int cl = t >> 4, pl4 = (t & 15) * 4;
    #pragma unroll
    for (int i = 0; i < 4; ++i) {
        float4 v = *(const float4*)&src[(size_t)(c0 + i * 16 + cl) * NPTS + p0 + pl4];
        tile[i * 16 + cl][pl4] = v.x; tile[i * 16 + cl][pl4 + 1] = v.y;
        tile[i * 16 + cl][pl4 + 2] = v.z; tile[i * 16 + cl][pl4 + 3] = v.w;
    }
    __syncthreads();
    int pl = t >> 2, cs = t & 3;
    float iv = inv[p0 + pl];
    alignas(16) unsigned short hbuf[16], lbuf[16];
    #pragma unroll
    for (int j = 0; j < 16; ++j) {
        float v = tile[cs * 16 + j][pl] * iv;
        unsigned short h = f2bf(v);
        hbuf[j] = h;
        lbuf[j] = f2bf(v - bf2f(h));
    }
    size_t ob = (size_t)(p0 + pl) * 256 + c0 + cs * 16;
    *(uint4*)&hiT[ob] = *(const uint4*)&hbuf[0];
    *(uint4*)&hiT[ob + 8] = *(const uint4*)&hbuf[8];
    *(uint4*)&loT[ob] = *(const uint4*)&lbuf[0];
    *(uint4*)&loT[ob + 8] = *(const uint4*)&lbuf[8];
}

// sim tile GEMM: 128x128 per block, split-bf16 3-term MFMA, global_load_lds dbuf.
// XCD-stripe swizzle: dispatch XCD = bid%8 (round-robin). Stripe s owns A-rows
// [s*9*128, +9*128); within XCD, blocks iterate cb-major (9 consecutive blocks
// share one B-tile). Per-XCD L2 working set ~3.3MB < 4MB -> A-stripe + hot
// B-tiles stay L2-local; cross-XCD fabric traffic drops ~16x.
__global__ __launch_bounds__(256) void sim_mfma_k(const unsigned short* __restrict__ AhT, const unsigned short* __restrict__ AlT,
                                                  const unsigned short* __restrict__ BhT, const unsigned short* __restrict__ BlT,
                                                  float4* __restrict__ prow, float4* __restrict__ pcol) {
    // 2 buffers x 4 streams x 128 rows x 32 elems (bf16) = 64 KB
    __shared__ __align__(16) unsigned short lds[32768];

    int bid = blockIdx.x;
    int s = bid & 7;
    int j = bid >> 3;
    int cb = j / STRIPE;
    int rb = s * STRIPE + (j % STRIPE);
    int p0 = rb * 128, q0 = cb * 128;
    int t = threadIdx.x;
    int lane = t & 63, w = t >> 6;
    int wr = w >> 1, wc = w & 1;
    int l15 = lane & 15, kslot = lane >> 4;

    // ---- staging geometry (global source pre-swizzled, LDS linear) ----
    int srow = w * 16 + (lane >> 2);           // 0..63 (chunk 0)
    int ssw = (srow >> 1) & 3;                 // same for srow+64
    int sgel = ((lane & 3) ^ ssw) * 8;         // swizzled element slot within 32-elem K-tile
    size_t gA0 = (size_t)(p0 + srow) * 256 + sgel;
    size_t gA1 = gA0 + (size_t)64 * 256;
    size_t gB0 = (size_t)(q0 + srow) * 256 + sgel;
    size_t gB1 = gB0 + (size_t)64 * 256;
    int lb0 = w * 512;                         // LDS elem base, chunk 0
    int lb1 = 2048 + w * 512;                  // chunk 1 (rows 64..127)

#define STAGE(b, kc) { size_t ko = (size_t)(kc) * 32; int bb = (b) * 16384; \
        gload16(AhT + gA0 + ko, &lds[bb          + lb0]); \
        gload16(AhT + gA1 + ko, &lds[bb          + lb1]); \
        gload16(AlT + gA0 + ko, &lds[bb +  4096  + lb0]); \
        gload16(AlT + gA1 + ko, &lds[bb +  4096  + lb1]); \
        gload16(BhT + gB0 + ko, &lds[bb +  8192  + lb0]); \
        gload16(BhT + gB1 + ko, &lds[bb +  8192  + lb1]); \
        gload16(BlT + gB0 + ko, &lds[bb + 12288  + lb0]); \
        gload16(BlT + gB1 + ko, &lds[bb + 12288  + lb1]); }

    STAGE(0, 0);

    f32x4 acc[4][4];
    #pragma unroll
    for (int i = 0; i < 4; ++i)
        #pragma unroll
        for (int j2 = 0; j2 < 4; ++j2) acc[i][j2] = (f32x4){0.f, 0.f, 0.f, 0.f};

    __syncthreads();   // drains vmcnt -> buf0 ready

    for (int kc = 0; kc < 8; ++kc) {
        if (kc < 7) STAGE((kc + 1) & 1, kc + 1);   // issue next-tile loads FIRST
        int bb = (kc & 1) * 16384;
        short8 ah[4], bh[4], xx[4];
        #pragma unroll
        for (int f = 0; f < 4; ++f) {
            int R = wr * 64 + f * 16 + l15;
            ah[f] = *(const short8*)&lds[bb + R * 32 + ((kslot ^ ((R >> 1) & 3)) << 3)];
        }
        #pragma unroll
        for (int f = 0; f < 4; ++f) {
            int R = wc * 64 + f * 16 + l15;
            bh[f] = *(const short8*)&lds[bb + 8192 + R * 32 + ((kslot ^ ((R >> 1) & 3)) << 3)];
        }
        #pragma unroll
        for (int i = 0; i < 4; ++i)
            #pragma unroll
            for (int j2 = 0; j2 < 4; ++j2)
                acc[i][j2] = __builtin_amdgcn_mfma_f32_16x16x32_bf16(ah[i], bh[j2], acc[i][j2], 0, 0, 0);
        #pragma unroll
        for (int f = 0; f < 4; ++f) {
            int R = wc * 64 + f * 16 + l15;
            xx[f] = *(const short8*)&lds[bb + 12288 + R * 32 + ((kslot ^ ((R >> 1) & 3)) << 3)];
        }
        #pragma unroll
        for (int i = 0; i < 4; ++i)
            #pragma unroll
            for (int j2 = 0; j2 < 4; ++j2)
                acc[i][j2] = __builtin_amdgcn_mfma_f32_16x16x32_bf16(ah[i], xx[j2], acc[i][j2], 0, 0, 0);
        #pragma unroll
        for (int f = 0; f < 4; ++f) {
            int R = wr * 64 + f * 16 + l15;
            xx[f] = *(const short8*)&lds[bb + 4096 + R * 32 + ((kslot ^ ((R >> 1) & 3)) << 3)];
        }
        #pragma unroll
        for (int i = 0; i < 4; ++i)
            #pragma unroll
            for (int j2 = 0; j2 < 4; ++j2)
                acc[i][j2] = __builtin_amdgcn_mfma_f32_16x16x32_bf16(xx[i], bh[j2], acc[i][j2], 0, 0, 0);
        __syncthreads();   // single barrier: drains this iter's gload_lds + ds_reads
    }

    // ---- fused top-2 reductions (LDS reused after final barrier) ----
    float4* rowred = (float4*)lds;          // [128][2]
    float4* colred = (float4*)lds + 256;    // [128][2]

    #pragma unroll
    for (int f = 0; f < 4; ++f) {
        #pragma unroll
        for (int r = 0; r < 4; ++r) {
            float v0 = -3.0e38f, v1 = -3.0e38f; int i0 = 0, i1 = 0;
            #pragma unroll
            for (int fc = 0; fc < 4; ++fc)
                feed(acc[f][fc][r], q0 + wc * 64 + fc * 16 + l15, v0, i0, v1, i1);
            #pragma unroll
            for (int m = 1; m < 16; m <<= 1) {
                float pv0 = __shfl_xor(v0, m); int pi0 = __shfl_xor(i0, m);
                float pv1 = __shfl_xor(v1, m); int pi1 = __shfl_xor(i1, m);
                feed(pv0, pi0, v0, i0, v1, i1);
                feed(pv1, pi1, v0, i0, v1, i1);
            }
            if (l15 == 0) {
                int row = wr * 64 + f * 16 + kslot * 4 + r;
                rowred[row * 2 + wc] = make_float4(v0, v1, __int_as_float(i0), __int_as_float(i1));
            }
        }
    }
    #pragma unroll
    for (int fc = 0; fc < 4; ++fc) {
        float v0 = -3.0e38f, v1 = -3.0e38f; int i0 = 0, i1 = 0;
        #pragma unroll
        for (int f = 0; f < 4; ++f)
            #pragma unroll
            for (int r = 0; r < 4; ++r)
                feed(acc[f][fc][r], p0 + wr * 64 + f * 16 + kslot * 4 + r, v0, i0, v1, i1);
        #pragma unroll
        for (int m = 16; m < 64; m <<= 1) {
            float pv0 = __shfl_xor(v0, m); int pi0 = __shfl_xor(i0, m);
            float pv1 = __shfl_xor(v1, m); int pi1 = __shfl_xor(i1, m);
            feed(pv0, pi0, v0, i0, v1, i1);
            feed(pv1, pi1, v0, i0, v1, i1);
        }
        if (kslot == 0) {
            int col = wc * 64 + fc * 16 + l15;
            colred[col * 2 + wr] = make_float4(v0, v1, __int_as_float(i0), __int_as_float(i1));
        }
    }
    __syncthreads();
    if (t < 128) {
        float4 a = rowred[t * 2], b = rowred[t * 2 + 1];
        float v0 = a.x, v1 = a.y; int i0 = __float_as_int(a.z), i1 = __float_as_int(a.w);
        feed(b.x, __float_as_int(b.z), v0, i0, v1, i1);
        feed(b.y, __float_as_int(b.w), v0, i0, v1, i1);
        prow[(size_t)cb * NPTS + p0 + t] = make_float4(v0, v1, __int_as_float(i0), __int_as_float(i1));
        float4 c = colred[t * 2], d = colred[t * 2 + 1];
        v0 = c.x; v1 = c.y; i0 = __float_as_int(c.z); i1 = __float_as_int(c.w);
        feed(d.x, __float_as_int(d.z), v0, i0, v1, i1);
        feed(d.y, __float_as_int(d.w), v0, i0, v1, i1);
        pcol[(size_t)rb * NPTS + q0 + t] = make_float4(v0, v1, __int_as_float(i0), __int_as_float(i1));
    }
}

__global__ void merge_rows_k(const float4* __restrict__ prow, int* __restrict__ nn12,
                             float* __restrict__ msim, float* __restrict__ r12) {
    int p = blockIdx.x * blockDim.x + threadIdx.x;
    if (p >= NPTS) return;
    float v0 = -3.0e38f, v1 = -3.0e38f; int i0 = 0, i1 = 0;
    for (int c = 0; c < RB; ++c) {
        float4 s = prow[(size_t)c * NPTS + p];
        feed(s.x, __float_as_int(s.z), v0, i0, v1, i1);
        feed(s.y, __float_as_int(s.w), v0, i0, v1, i1);
    }
    nn12[p] = i0; msim[p] = v0;
    r12[p] = (2.0f - 2.0f * v0) / ((2.0f - 2.0f * v1) + 1e-8f);
}

__global__ void merge_cols_k(const float4* __restrict__ pcol, int* __restrict__ nn21, float* __restrict__ r21) {
    int q = blockIdx.x * blockDim.x + threadIdx.x;
    if (q >= NPTS) return;
    float v0 = -3.0e38f, v1 = -3.0e38f; int i0 = 0, i1 = 0;
    for (int k = 0; k < RB; ++k) {
        float4 s = pcol[(size_t)k * NPTS + q];
        feed(s.x, __float_as_int(s.z), v0, i0, v1, i1);
        feed(s.y, __float_as_int(s.w), v0, i0, v1, i1);
    }
    nn21[q] = i0;
    r21[q] = (2.0f - 2.0f * v0) / ((2.0f - 2.0f * v1) + 1e-8f);
}

__global__ void valid_k(const int* __restrict__ nn12, const float* __restrict__ r12,
                        const int* __restrict__ nn21, const float* __restrict__ r21,
                        int* __restrict__ validv) {
    int p = blockIdx.x * blockDim.x + threadIdx.x;
    if (p >= NPTS) return;
    int nn = nn12[p];
    bool mnn = (nn21[nn] == p) && (r12[p] <= 0.95f) && (r21[nn] <= 0.95f);
    int xA = p % WW, yA = p / WW, xB = nn % WW, yB = nn / WW;
    bool disc = (xA == 0) | (xA == WW - 1) | (yA == 0) | (yA == WW - 1) |
                (xB == 0) | (xB == WW - 1) | (yB == 0) | (yB == WW - 1);
    validv[p] = (mnn && !disc) ? 1 : 0;
}

// one block (256 threads = 256 channels) per point
__global__ __launch_bounds__(256) void refine_k(const float* __restrict__ actA, const float* __restrict__ actB,
                                                const int* __restrict__ nn12, const float* __restrict__ msim,
                                                const int* __restrict__ validv, float* __restrict__ out) {
    int n = blockIdx.x;
    int c = threadIdx.x;
    int val = validv[n];
    int nn = nn12[n];
    int xA = n % WW, yA = n / WW;
    int xB = nn % WW, yB = nn / WW;
    int pAx = val ? 2 * xA : 2, pAy = val ? 2 * yA : 2;
    int pBx = val ? 2 * xB : 2, pBy = val ? 2 * yB : 2;
    const int nxv[4] = {0, 0, 1, 1};
    const int nyv[4] = {0, 1, 0, 1};
    float a[4], b[4];
    #pragma unroll
    for (int i = 0; i < 4; ++i) {
        a[i] = actA[(size_t)c * MACT + (pAy + nyv[i]) * W2 + pAx + nxv[i]];
        b[i] = actB[(size_t)c * MACT + (pBy + nyv[i]) * W2 + pBx + nxv[i]];
    }
    float vals[24];
    #pragma unroll
    for (int i = 0; i < 4; ++i) vals[i] = a[i] * a[i];
    #pragma unroll
    for (int j = 0; j < 4; ++j) vals[4 + j] = b[j] * b[j];
    #pragma unroll
    for (int i = 0; i < 4; ++i)
        #pragma unroll
        for (int j = 0; j < 4; ++j) vals[8 + i * 4 + j] = a[i] * b[j];
    #pragma unroll
    for (int v = 0; v < 24; ++v) {
        float x = vals[v];
        #pragma unroll
        for (int m = 1; m < 64; m <<= 1) x += __shfl_xor(x, m);
        vals[v] = x;
    }
    __shared__ float part[24][4];
    __shared__ float fin[24];
    int wave = c >> 6, lane = c & 63;
    if (lane == 0) {
        #pragma unroll
        for (int v = 0; v < 24; ++v) part[v][wave] = vals[v];
    }
    __syncthreads();
    if (c < 24) fin[c] = part[c][0] + part[c][1] + part[c][2] + part[c][3];
    __syncthreads();
    if (c == 0) {
        float rsA[4], rsB[4], sc[4][4];
        #pragma unroll
        for (int i = 0; i < 4; ++i) rsA[i] = 1.0f / sqrtf(fin[i]);
        #pragma unroll
        for (int j = 0; j < 4; ++j) rsB[j] = 1.0f / sqrtf(fin[4 + j]);
        #pragma unroll
        for (int i = 0; i < 4; ++i)
            #pragma unroll
            for (int j = 0; j < 4; ++j) sc[i][j] = fin[8 + i * 4 + j] * rsA[i] * rsB[j];

        float ratA[4], scoreA[4]; int mAB[4];
        #pragma unroll
        for (int i = 0; i < 4; ++i) {
            float v0 = -3.0e38f, v1 = -3.0e38f; int i0 = 0, i1 = 0;
            #pragma unroll
            for (int j = 0; j < 4; ++j) feed(sc[i][j], j, v0, i0, v1, i1);
            float d0 = 2.0f - 2.0f * v0, d1 = 2.0f - 2.0f * v1;
            ratA[i] = d0 / (d1 + 1e-8f);
            scoreA[i] = d0; mAB[i] = i0;
        }
        float ratB[4]; int mBA[4];
        #pragma unroll
        for (int j = 0; j < 4; ++j) {
            float v0 = -3.0e38f, v1 = -3.0e38f; int i0 = 0, i1 = 0;
            #pragma unroll
            for (int i = 0; i < 4; ++i) feed(sc[i][j], i, v0, i0, v1, i1);
            float d0 = 2.0f - 2.0f * v0, d1 = 2.0f - 2.0f * v1;
            ratB[j] = d0 / (d1 + 1e-8f);
            mBA[j] = i0;
        }
        bool rm[4];
        #pragma unroll
        for (int i = 0; i < 4; ++i) {
            bool cyc = (mBA[mAB[i]] == i);
            rm[i] = (fmaxf(ratA[i], ratB[i]) < 0.9f) && cyc;
        }
        float sm[4];
        #pragma unroll
        for (int i = 0; i < 4; ++i) sm[i] = rm[i] ? scoreA[i] : 5.0f;
        {
            float v0 = -3.0e38f, v1 = -3.0e38f; int i0 = 0, i1 = 0;
            #pragma unroll
            for (int i = 0; i < 4; ++i) feed(sm[i], i, v0, i0, v1, i1);
            rm[i0] = false; rm[i1] = false;
        }
        out[n * 5 + 0] = msim[n];
        #pragma unroll
        for (int i = 0; i < 4; ++i) out[n * 5 + 1 + i] = sm[i];
        size_t b2 = (size_t)NPTS * 5;
        #pragma unroll
        for (int i = 0; i < 4; ++i) out[b2 + (size_t)n * 4 + i] = (float)(pAx + nxv[i]);
        #pragma unroll
        for (int i = 0; i < 4; ++i) out[b2 + (size_t)NPTS * 4 + (size_t)n * 4 + i] = (float)(pAy + nyv[i]);
        size_t b3 = b2 + (size_t)NPTS * 8;
        #pragma unroll
        for (int i = 0; i < 4; ++i) out[b3 + (size_t)n * 4 + i] = (float)(pBx + nxv[mAB[i]]);
        #pragma unroll
        for (int i = 0; i < 4; ++i) out[b3 + (size_t)NPTS * 4 + (size_t)n * 4 + i] = (float)(pBy + nyv[mAB[i]]);
        size_t b4 = b3 + (size_t)NPTS * 8;
        #pragma unroll
        for (int i = 0; i < 4; ++i) out[b4 + (size_t)n * 4 + i] = (rm[i] && val) ? 1.0f : 0.0f;
    }
}

extern "C" void kernel_launch(void* const* d_in, const int* in_sizes, int n_in,
                              void* d_out, int out_size, void* d_ws, size_t ws_size,
                              hipStream_t stream) {
    const float* mapA = (const float*)d_in[0];
    const float* mapB = (const float*)d_in[1];
    const float* actA = (const float*)d_in[2];
    const float* actB = (const float*)d_in[3];
    float* out = (float*)d_out;

    char* wsb = (char*)d_ws;
    size_t szT = (size_t)NPTS * 256 * sizeof(unsigned short);  // 4.72MB
    unsigned short* AhT = (unsigned short*)wsb;            wsb += szT;
    unsigned short* AlT = (unsigned short*)wsb;            wsb += szT;
    unsigned short* BhT = (unsigned short*)wsb;            wsb += szT;
    unsigned short* BlT = (unsigned short*)wsb;            wsb += szT;
    float4* prow = (float4*)wsb;                           wsb += (size_t)RB * NPTS * sizeof(float4);
    float4* pcol = (float4*)wsb;                           wsb += (size_t)RB * NPTS * sizeof(float4);
    float* invA = (float*)wsb;                             wsb += NPTS * sizeof(float);
    float* invB = (float*)wsb;                             wsb += NPTS * sizeof(float);
    int* nn12 = (int*)wsb;                                 wsb += NPTS * sizeof(int);
    float* msim = (float*)wsb;                             wsb += NPTS * sizeof(float);
    float* r12 = (float*)wsb;                              wsb += NPTS * sizeof(float);
    int* nn21 = (int*)wsb;                                 wsb += NPTS * sizeof(int);
    float* r21 = (float*)wsb;                              wsb += NPTS * sizeof(float);
    int* validv = (int*)wsb;

    norm_inv_k<<<NPTS / 256, 256, 0, stream>>>(mapA, invA);
    norm_inv_k<<<NPTS / 256, 256, 0, stream>>>(mapB, invB);
    dim3 gp(NPTS / 64, CDIM / 64);
    prep_split_k<<<gp, 256, 0, stream>>>(mapA, invA, AhT, AlT);
    prep_split_k<<<gp, 256, 0, stream>>>(mapB, invB, BhT, BlT);
    sim_mfma_k<<<RB * RB, 256, 0, stream>>>(AhT, AlT, BhT, BlT, prow, pcol);
    merge_rows_k<<<NPTS / 256, 256, 0, stream>>>(prow, nn12, msim, r12);
    merge_cols_k<<<NPTS / 256, 256, 0, stream>>>(pcol, nn21, r21);
    valid_k<<<NPTS / 256, 256, 0, stream>>>(nn12, r12, nn21, r21, validv);
    refine_k<<<NPTS, 256, 0, stream>>>(actA, actB, nn12, msim, validv, out);
}